// Round 5
// baseline (312.447 us; speedup 1.0000x reference)
//
#include <hip/hip_runtime.h>
#include <hip/hip_bf16.h>
#include <stdint.h>

#define F_DIM 256
#define H_DIM 384
#define L_DIM 64
#define O_DIM 16
#define E_NUM 5
#define BM 32
#define T_TILES 4

#define XK_STRIDE 264   // bf16 elems (256 + 8 pad)
#define H_STRIDE 392    // bf16 elems (384 + 8 pad)
#define LAT_STRIDE 33   // f32 elems (32 + 1 pad)
#define MU_STRIDE 328   // bf16 elems (320 + 8 pad)

typedef short bf16x8 __attribute__((ext_vector_type(8)));
typedef float f32x4 __attribute__((ext_vector_type(4)));

__device__ __forceinline__ unsigned short f2bf(float f) {
    union { float f; unsigned int u; } v; v.f = f;
    unsigned int u = v.u;
    return (unsigned short)((u + 0x7FFFu + ((u >> 16) & 1u)) >> 16);
}

__device__ __forceinline__ unsigned int pk2(float a, float b) {
#if defined(__has_builtin)
#if __has_builtin(__builtin_amdgcn_cvt_pk_bf16_f32)
    typedef __bf16 bf2 __attribute__((ext_vector_type(2)));
    bf2 p = __builtin_amdgcn_cvt_pk_bf16_f32(a, b);
    union { bf2 v; unsigned int u; } c; c.v = p;
    return c.u;
#else
    return (unsigned int)f2bf(a) | ((unsigned int)f2bf(b) << 16);
#endif
#else
    return (unsigned int)f2bf(a) | ((unsigned int)f2bf(b) << 16);
#endif
}

__device__ __forceinline__ uint2 cvt4(float4 v) {
    uint2 r; r.x = pk2(v.x, v.y); r.y = pk2(v.z, v.w); return r;
}

#define KLOG2E (-1.44269504088896f)
// sigmoid(a + b) with kb = KLOG2E*b precomputed: rcp(1 + 2^(K*a + kb))
__device__ __forceinline__ float sig2(float a, float kb) {
    return __builtin_amdgcn_rcpf(1.0f + __builtin_amdgcn_exp2f(fmaf(a, KLOG2E, kb)));
}

// ============================ prep ============================
// Weights in MFMA A-fragment order: Wf[tile][ks][lane][8],
//   element j of lane (q,c) = W^T[tile*16 + c][ks*32 + q*8 + j]
__global__ void prep_kernel(const float* __restrict__ W1, const float* __restrict__ W2,
                            const float* __restrict__ pi,
                            unsigned short* __restrict__ W1f,
                            unsigned short* __restrict__ W2f,
                            unsigned short* __restrict__ piTf) {
    __shared__ float tile[32][33];   // [k_local][row_local]
    const int b = blockIdx.x;
    const int tid = threadIdx.x;
    const int tx = tid & 31, ty = tid >> 5;

    if (b < 120) {
        int ks, t0, nks;
        unsigned short* dst;
        if (b < 96) {
            const int fb = b / 12, hb = b % 12;
            #pragma unroll
            for (int s = 0; s < 32; s += 8)
                tile[ty + s][tx] = W1[(size_t)(fb * 32 + ty + s) * H_DIM + hb * 32 + tx];
            ks = fb; t0 = hb * 2; nks = 8; dst = W1f;
        } else {
            const int bb = b - 96, hb = bb / 2, lb = bb % 2;
            #pragma unroll
            for (int s = 0; s < 32; s += 8)
                tile[ty + s][tx] = W2[(size_t)(hb * 32 + ty + s) * L_DIM + lb * 32 + tx];
            ks = hb; t0 = lb * 2; nks = 12; dst = W2f;
        }
        __syncthreads();
        const int t_local = tid >> 7;
        const int r = (tid * 2) & 255;
        const int lane = r >> 2;
        const int e2b = r & 3;
        const int q = lane >> 4, c = lane & 15;
        const int f0 = q * 8 + e2b * 2;
        const int hl = t_local * 16 + c;
        uint2 v;
        v.x = pk2(tile[f0 + 0][hl], tile[f0 + 1][hl]);
        v.y = pk2(tile[f0 + 2][hl], tile[f0 + 3][hl]);
        const size_t off = ((size_t)((t0 + t_local) * nks + ks) * 64 + lane) * 8 + e2b * 2;
        *(uint2*)(dst + off) = v;
    } else {
        for (int i = tid; i < O_DIM * E_NUM * L_DIM; i += 256) {
            const int j = i & 7, lane = (i >> 3) & 63, ks = i >> 9;
            const int q = lane >> 4, c = lane & 15;
            const int k = ks * 32 + q * 8 + j;
            piTf[i] = f2bf(pi[k * O_DIM + c] * 0.2f);
        }
    }
}

// ============================ fused ============================
__global__ __launch_bounds__(256, 4) void fused_kernel(
    const float* __restrict__ X,
    const unsigned short* __restrict__ W1f,
    const float* __restrict__ b1,
    const unsigned short* __restrict__ W2f,
    const float* __restrict__ b2,
    const int* __restrict__ phi,
    const unsigned short* __restrict__ piTf,
    float* __restrict__ out) {

    __shared__ __align__(16) unsigned char smem[34816];
    unsigned short* Xs  = (unsigned short*)smem;            // [32][264] 16896 B
    unsigned short* Hs  = (unsigned short*)smem;            // [32][392] 25088 B (after Xs dead)
    float*          latT = (float*)(smem + 25088);          // [64][33]   8448 B
    int*            phis = (int*)(smem + 33536);            // 1280 B -> 34816 total
    unsigned short* mus = (unsigned short*)smem;            // [32][328] 20992 B (after Hs dead)

    const int tid  = threadIdx.x;
    const int wave = tid >> 6;
    const int lane = tid & 63;
    const int q    = lane >> 4;
    const int c    = lane & 15;
    const int blockRow0 = blockIdx.x * (BM * T_TILES);

    for (int idx = tid; idx < E_NUM * L_DIM; idx += 256) phis[idx] = phi[idx];

    // preamble: load X rows for tile 0
    float4 f4[8];
    #pragma unroll
    for (int i = 0; i < 8; ++i)
        f4[i] = *(const float4*)(X + (size_t)(blockRow0 + wave * 8 + i) * F_DIM + lane * 4);

    for (int it = 0; it < T_TILES; ++it) {
        const int row0 = blockRow0 + it * BM;

        // ---- store current tile X -> Xs (bf16). Xs region safe: B6/B1 ordering.
        #pragma unroll
        for (int i = 0; i < 8; ++i)
            *(uint2*)&Xs[(wave * 8 + i) * XK_STRIDE + lane * 4] = cvt4(f4[i]);

        __syncthreads();   // B1: Xs + phis ready

        // ================= GEMM1: D[n][m] = sum_k W1T[n][k] * Xs[m][k] =================
        f32x4 acc[6][2];
        #pragma unroll
        for (int i = 0; i < 6; ++i)
            #pragma unroll
            for (int j = 0; j < 2; ++j)
                acc[i][j] = (f32x4){0.f, 0.f, 0.f, 0.f};

        #pragma unroll 2
        for (int ks = 0; ks < 8; ++ks) {
            bf16x8 af[6];
            #pragma unroll
            for (int i = 0; i < 6; ++i)
                af[i] = *(const bf16x8*)(W1f + ((size_t)(wave * 48 + i * 8 + ks) * 64 + lane) * 8);
            bf16x8 bf_[2];
            #pragma unroll
            for (int j = 0; j < 2; ++j)
                bf_[j] = *(const bf16x8*)&Xs[(j * 16 + c) * XK_STRIDE + ks * 32 + q * 8];
            #pragma unroll
            for (int i = 0; i < 6; ++i)
                #pragma unroll
                for (int j = 0; j < 2; ++j)
                    acc[i][j] = __builtin_amdgcn_mfma_f32_16x16x32_bf16(af[i], bf_[j], acc[i][j], 0, 0, 0);
        }
        __syncthreads();   // B2: Xs reads done; Hs (aliases) writable

        // ---- prefetch next tile's X into registers (lands during epilogue/GEMM2/tree)
        if (it < T_TILES - 1) {
            const int nrow0 = blockRow0 + (it + 1) * BM;
            #pragma unroll
            for (int i = 0; i < 8; ++i)
                f4[i] = *(const float4*)(X + (size_t)(nrow0 + wave * 8 + i) * F_DIM + lane * 4);
        }

        // ---- GEMM1 epilogue: sigmoid -> Hs bf16
        const int nbase = wave * 96;
        #pragma unroll
        for (int i = 0; i < 6; ++i) {
            const int n0 = nbase + i * 16 + q * 4;
            float4 bv = *(const float4*)(b1 + n0);
            const float kb0 = KLOG2E * bv.x, kb1 = KLOG2E * bv.y;
            const float kb2 = KLOG2E * bv.z, kb3 = KLOG2E * bv.w;
            #pragma unroll
            for (int j = 0; j < 2; ++j) {
                const int m = j * 16 + c;
                uint2 h2;
                h2.x = pk2(sig2(acc[i][j][0], kb0), sig2(acc[i][j][1], kb1));
                h2.y = pk2(sig2(acc[i][j][2], kb2), sig2(acc[i][j][3], kb3));
                *(uint2*)&Hs[m * H_STRIDE + n0] = h2;
            }
        }
        __syncthreads();   // B3: Hs complete

        // ================= GEMM2: D[l][m] = sum_h W2T[l][h] * Hs[m][h] =================
        {
            bf16x8 wfrag[12];
            #pragma unroll
            for (int ks = 0; ks < 12; ++ks)
                wfrag[ks] = *(const bf16x8*)(W2f + ((size_t)(wave * 12 + ks) * 64 + lane) * 8);
            f32x4 acc2[2];
            acc2[0] = (f32x4){0.f, 0.f, 0.f, 0.f};
            acc2[1] = (f32x4){0.f, 0.f, 0.f, 0.f};
            #pragma unroll
            for (int ks = 0; ks < 12; ++ks) {
                #pragma unroll
                for (int j = 0; j < 2; ++j) {
                    bf16x8 bf_ = *(const bf16x8*)&Hs[(j * 16 + c) * H_STRIDE + ks * 32 + q * 8];
                    acc2[j] = __builtin_amdgcn_mfma_f32_16x16x32_bf16(wfrag[ks], bf_, acc2[j], 0, 0, 0);
                }
            }
            const int lb = wave * 16;
            const float4 b2v = *(const float4*)(b2 + lb + q * 4);
            const float kb0 = KLOG2E * b2v.x, kb1 = KLOG2E * b2v.y;
            const float kb2 = KLOG2E * b2v.z, kb3 = KLOG2E * b2v.w;
            #pragma unroll
            for (int j = 0; j < 2; ++j) {
                const int m = j * 16 + c;
                const int l0 = lb + q * 4;
                latT[(l0 + 0) * LAT_STRIDE + m] = sig2(acc2[j][0], kb0);
                latT[(l0 + 1) * LAT_STRIDE + m] = sig2(acc2[j][1], kb1);
                latT[(l0 + 2) * LAT_STRIDE + m] = sig2(acc2[j][2], kb2);
                latT[(l0 + 3) * LAT_STRIDE + m] = sig2(acc2[j][3], kb3);
            }
        }
        __syncthreads();   // B4: latT complete; Hs dead -> mus writable

        // ================= stage 3a: tree routing, static DFS (7 live regs, not mu[64]) =================
        {
            const int r = lane & 31;
            const int e = wave * 2 + (lane >> 5);
            if (e < E_NUM) {
                const int base = e * 64;
                // node (lev, prefix): d = latT[phis[base + (1<<lev) + prefix]*LAT_STRIDE + r]
                const float d0 = latT[phis[base + 1] * LAT_STRIDE + r];
                #pragma unroll
                for (int b0 = 0; b0 < 2; ++b0) {
                    const float p1 = b0 ? (1.0f - d0) : d0;
                    const float d1 = latT[phis[base + 2 + b0] * LAT_STRIDE + r];
                    #pragma unroll
                    for (int b1 = 0; b1 < 2; ++b1) {
                        const int i2 = b0 * 2 + b1;
                        const float p2 = p1 * (b1 ? (1.0f - d1) : d1);
                        const float d2 = latT[phis[base + 4 + i2] * LAT_STRIDE + r];
                        #pragma unroll
                        for (int b2 = 0; b2 < 2; ++b2) {
                            const int i3 = i2 * 2 + b2;
                            const float p3 = p2 * (b2 ? (1.0f - d2) : d2);
                            const float d3 = latT[phis[base + 8 + i3] * LAT_STRIDE + r];
                            #pragma unroll
                            for (int b3 = 0; b3 < 2; ++b3) {
                                const int i4 = i3 * 2 + b3;
                                const float p4 = p3 * (b3 ? (1.0f - d3) : d3);
                                const float d4 = latT[phis[base + 16 + i4] * LAT_STRIDE + r];
                                uint2 w2;
                                #pragma unroll
                                for (int b4 = 0; b4 < 2; ++b4) {
                                    const int i5 = i4 * 2 + b4;
                                    const float p5 = p4 * (b4 ? (1.0f - d4) : d4);
                                    const float d5 = latT[phis[base + 32 + i5] * LAT_STRIDE + r];
                                    const unsigned int w = pk2(p5 * d5, p5 * (1.0f - d5));
                                    if (b4 == 0) w2.x = w; else w2.y = w;
                                }
                                // 4 leaves (i4*4 .. i4*4+3), 8 bytes, 8B-aligned
                                *(uint2*)&mus[r * MU_STRIDE + e * 64 + i4 * 4] = w2;
                            }
                        }
                    }
                }
            }
        }
        __syncthreads();   // B5: mus complete

        // ================= stage 3b: out[m][o] = sum_k mus[m][k] * piT[o][k] =================
        if (wave < 2) {
            const int mt = wave;
            bf16x8 pfrag[10];
            #pragma unroll
            for (int ks = 0; ks < 10; ++ks)
                pfrag[ks] = *(const bf16x8*)(piTf + ((size_t)ks * 64 + lane) * 8);
            f32x4 acc3 = (f32x4){0.f, 0.f, 0.f, 0.f};
            #pragma unroll
            for (int ks = 0; ks < 10; ++ks) {
                bf16x8 af = *((const bf16x8*)&mus[(mt * 16 + c) * MU_STRIDE + ks * 32 + q * 8]);
                acc3 = __builtin_amdgcn_mfma_f32_16x16x32_bf16(af, pfrag[ks], acc3, 0, 0, 0);
            }
            #pragma unroll
            for (int rg = 0; rg < 4; ++rg) {
                const int m = mt * 16 + q * 4 + rg;
                out[(size_t)(row0 + m) * O_DIM + c] = acc3[rg];
            }
        }
        __syncthreads();   // B6: mus reads done; Xs writable next iteration
    }
}

extern "C" void kernel_launch(void* const* d_in, const int* in_sizes, int n_in,
                              void* d_out, int out_size, void* d_ws, size_t ws_size,
                              hipStream_t stream) {
    (void)in_sizes; (void)n_in; (void)out_size; (void)ws_size;
    const float* X  = (const float*)d_in[0];
    const float* W1 = (const float*)d_in[1];
    const float* b1 = (const float*)d_in[2];
    const float* W2 = (const float*)d_in[3];
    const float* b2 = (const float*)d_in[4];
    const int*   phi = (const int*)d_in[5];
    const float* pi  = (const float*)d_in[6];
    float* out = (float*)d_out;

    unsigned short* W1f  = (unsigned short*)d_ws;                           // 196608 B
    unsigned short* W2f  = (unsigned short*)((char*)d_ws + 196608);         //  49152 B
    unsigned short* piTf = (unsigned short*)((char*)d_ws + 196608 + 49152); //  10240 B

    prep_kernel<<<121, 256, 0, stream>>>(W1, W2, pi, W1f, W2f, piTf);

    const int nblocks = 131072 / (BM * T_TILES);  // 1024
    fused_kernel<<<nblocks, 256, 0, stream>>>(X, W1f, b1, W2f, b2, phi, piTf, out);
}